// Round 13
// baseline (352.818 us; speedup 1.0000x reference)
//
#include <hip/hip_runtime.h>
#include <math.h>

#define Bx 16
#define Cx 64
#define Hx 128
#define Wx 128
#define HWx (Hx * Wx)

#define TW 32
#define TH 8
#define CCH 8
#define HALO_W (TW + 2)
#define HALO_H (TH + 2)
#define CPLANE (HALO_H * HALO_W)          // 340
#define CHUNK_ELEMS (CCH * CPLANE)        // 2720
#define NCHUNK (Cx / CCH)                 // 8

// workspace layout (float/u32 offsets)
#define WS_CWB   0                         // 1x1 B-fragments bf16: 8 tiles*64 lanes*4 u32 = 2048
#define WS_GPACK 2048                      // gpack8[c*72 + k*8 + rg]  4608   (rg=r*2+g)
#define WS_KERN  6656                      // per-b [c*36+k*4+g]       16*2304 = 36864
#define WS_ATT   43520                     // per-b [c*4+r]            16*256  = 4096

typedef short bf16x8 __attribute__((ext_vector_type(8)));
typedef float f32x4  __attribute__((ext_vector_type(4)));
typedef unsigned int u32x4 __attribute__((ext_vector_type(4)));

__device__ __host__ inline unsigned rne_bf16(float f) {
    union { float f; unsigned u; } v; v.f = f;
    return (v.u + 0x7fffu + ((v.u >> 16) & 1u)) >> 16;
}

// rbuf row swizzle: 4 slots of 16B per 64B pixel row
#define RSWZ(p) ((((p) & 3) ^ (((p) >> 2) & 3)))

// ---------------- prep: hypernetwork + weight repacking ----------------
__global__ __launch_bounds__(256)
void da_prep(const float* __restrict__ x_deg,
             const float* __restrict__ kw1,
             const float* __restrict__ kw2,
             const float* __restrict__ convw,
             const float* __restrict__ ca_w1,
             const float* __restrict__ ca_w2,
             const float* __restrict__ g1w,
             const float* __restrict__ g2w,
             float* __restrict__ ws)
{
    const int b = blockIdx.x;
    const int tid = threadIdx.x;
    unsigned int* wsu = (unsigned int*)ws;

    if (b == Bx) {
        // 1x1 weights as MFMA B-fragments, bf16 RNE (R12-validated layout).
        for (int i = tid; i < 2048; i += 256) {
            const int t    = i >> 8;
            const int rem  = i & 255;
            const int lane = rem >> 2;
            const int w    = rem & 3;
            const int nt = t >> 1, ks = t & 1;
            const int o = nt * 16 + (lane & 15);
            const int c = ks * 32 + ((lane >> 4) << 3) + w * 2;
            const unsigned lo = rne_bf16(convw[o * 64 + c]);
            const unsigned hi = rne_bf16(convw[o * 64 + c + 1]);
            wsu[WS_CWB + i] = lo | (hi << 16);
        }
        // guide weights packed [c][k][8rg]: per-k 8 floats = 2 aligned float4
        for (int i = tid; i < 4608; i += 256) {
            const int c = i / 72;
            const int rem = i - c * 72;
            const int k  = rem >> 3;
            const int rg = rem & 7;
            const int r = rg >> 1;
            const int g = rg & 1;
            const float* src = g ? g2w : g1w;
            ws[WS_GPACK + i] = src[(r * Cx + c) * 9 + k];
        }
        return;
    }

    __shared__ float h1[16];
    __shared__ float a1[16];
    if (tid < 32) {
        const int j = tid & 15;
        const float* wsrc = (tid < 16) ? (kw1 + j * Cx) : (ca_w1 + j * Cx);
        float acc = 0.f;
        #pragma unroll 8
        for (int c = 0; c < Cx; ++c) acc = fmaf(x_deg[b * Cx + c], wsrc[c], acc);
        acc = acc > 0.f ? acc : 0.1f * acc;               // leaky_relu 0.1
        if (tid < 16) h1[j] = acc; else a1[j] = acc;
    }
    __syncthreads();

    for (int o4 = tid; o4 < 4 * 576; o4 += 256) {
        const int g = o4 / 576;
        const int o = o4 - g * 576;
        float acc = 0.f;
        #pragma unroll
        for (int i = 0; i < 4; ++i)
            acc = fmaf(h1[g * 4 + i], kw2[(g * 576 + o) * 4 + i], acc);
        const int c = o / 9;
        const int k = o - c * 9;
        ws[WS_KERN + b * 2304 + c * 36 + k * 4 + g] = acc;
    }
    {
        const int r = tid >> 6;
        const int c = tid & 63;
        float acc = 0.f;
        #pragma unroll
        for (int i = 0; i < 4; ++i)
            acc = fmaf(a1[r * 4 + i], ca_w2[(r * Cx + c) * 4 + i], acc);
        ws[WS_ATT + b * 256 + c * 4 + r] = 1.f / (1.f + expf(-acc));
    }
}

// ---------------- main fused kernel: R12 + LDS diet -> 3 blocks/CU ----------------
// Changes vs R12 (146us clean): (1) rbuf halved via K-split GEMM (acc[4][4]
// lives across phase-separated staging - R10-proven pattern); (2) y[64]
// deleted - epilogue consumes transpose per nt-group; (3) gpack [c][k][8]
// (-25% weight b128 reads, bit-identical fma chains); (4) sy aliased into
// dead sx+rbuf pool. LDS 76.8 -> ~45 KB. Argmax path bit-identical.
__global__ __launch_bounds__(256, 3)
void da_main(const float* __restrict__ x0,
             const float* __restrict__ ws,
             const float* __restrict__ g1b,
             const float* __restrict__ g2b,
             const float* __restrict__ convb,
             float* __restrict__ out)
{
    const int b  = blockIdx.z;
    const int h0 = blockIdx.y * TH;
    const int w0 = blockIdx.x * TW;
    const int tid = threadIdx.x;
    const int tx = tid & (TW - 1);
    const int ty = tid >> 5;
    const int lane = tid & 63;
    const int wave = tid >> 6;

    // swts: pass1 = gpack [c][k][8] (4608 floats, 18 KB)
    //       pass2 overlay = skern[0,2304) + satt[2304,2560)
    __shared__ __align__(16) float swts[4608];
    // pool: sx float[2720] @0 | rbuf 16KB @10880B ; sy (4x1088 fl) aliased @0 after GEMM
    __shared__ __align__(16) char pool[27264];
    float* sx = (float*)pool;
    char*  rbuf = pool + 10880;
    float* sy = (float*)pool;
    // total LDS ~44.6 KB -> 3 blocks/CU

    const float* xb  = x0 + (size_t)b * Cx * HWx;
    const float* kws = ws + WS_KERN + b * 2304;
    const float* aws = ws + WS_ATT  + b * 256;
    const unsigned int* wsu = (const unsigned int*)ws;

    // --- per-thread staging offsets, computed ONCE (named ints, no array) ---
    int o0, o1, o2, o3, o4, o5, o6, o7, o8, o9, o10;
    unsigned vmask = 0u;
#define MKOFF(i, oname)                                                        \
    do {                                                                       \
        const int e   = tid + (i) * 256;                                       \
        const int cc  = e / CPLANE;                                            \
        const int rem = e - cc * CPLANE;                                       \
        const int row = rem / HALO_W;                                          \
        const int col = rem - row * HALO_W;                                    \
        const int gh  = h0 - 1 + row;                                          \
        const int gw  = w0 - 1 + col;                                          \
        oname = cc * HWx + gh * Wx + gw;                                       \
        if (e < CHUNK_ELEMS && (unsigned)gh < Hx && (unsigned)gw < Wx)         \
            vmask |= (1u << (i));                                              \
    } while (0)
    MKOFF(0, o0);  MKOFF(1, o1);  MKOFF(2, o2);  MKOFF(3, o3);
    MKOFF(4, o4);  MKOFF(5, o5);  MKOFF(6, o6);  MKOFF(7, o7);
    MKOFF(8, o8);  MKOFF(9, o9);  MKOFF(10, o10);
#undef MKOFF

    // batched staging: issue all loads, then all LDS writes (R10-proven)
#define STAGE_CHUNK(ch)                                                        \
    do {                                                                       \
        const float* src = xb + (size_t)(ch) * CCH * HWx;                      \
        float v0 = 0.f, v1 = 0.f, v2 = 0.f, v3 = 0.f, v4 = 0.f, v5 = 0.f;     \
        float v6 = 0.f, v7 = 0.f, v8 = 0.f, v9 = 0.f, v10 = 0.f;              \
        if (vmask & 1u)      v0  = src[o0];                                    \
        if (vmask & 2u)      v1  = src[o1];                                    \
        if (vmask & 4u)      v2  = src[o2];                                    \
        if (vmask & 8u)      v3  = src[o3];                                    \
        if (vmask & 16u)     v4  = src[o4];                                    \
        if (vmask & 32u)     v5  = src[o5];                                    \
        if (vmask & 64u)     v6  = src[o6];                                    \
        if (vmask & 128u)    v7  = src[o7];                                    \
        if (vmask & 256u)    v8  = src[o8];                                    \
        if (vmask & 512u)    v9  = src[o9];                                    \
        if (vmask & 1024u)   v10 = src[o10];                                   \
        sx[tid]           = v0;   sx[tid + 256]  = v1;                         \
        sx[tid + 512]     = v2;   sx[tid + 768]  = v3;                         \
        sx[tid + 1024]    = v4;   sx[tid + 1280] = v5;                         \
        sx[tid + 1536]    = v6;   sx[tid + 1792] = v7;                         \
        sx[tid + 2048]    = v8;   sx[tid + 2304] = v9;                         \
        if (tid < CHUNK_ELEMS - 2560) sx[tid + 2560] = v10;                    \
    } while (0)

    // --- prologue: gpack (1152 float4) batched into LDS ---
    {
        const float4* s4 = (const float4*)(ws + WS_GPACK);
        float4* d4 = (float4*)swts;
        const float4 g0 = s4[tid], g1 = s4[tid + 256];
        const float4 g2 = s4[tid + 512], g3 = s4[tid + 768];
        float4 g4 = (float4){0.f, 0.f, 0.f, 0.f};
        if (tid < 128) g4 = s4[tid + 1024];
        d4[tid] = g0; d4[tid + 256] = g1; d4[tid + 512] = g2; d4[tid + 768] = g3;
        if (tid < 128) d4[tid + 1024] = g4;
    }

    // ================= PASS 1: guide convs -> argmax =================
    float ga[8];
    #pragma unroll
    for (int r = 0; r < 4; ++r) { ga[r] = g1b[r]; ga[4 + r] = g2b[r]; }

    #pragma unroll 1
    for (int ch = 0; ch < NCHUNK; ++ch) {
        __syncthreads();
        STAGE_CHUNK(ch);
        __syncthreads();

        float pg[8] = {0.f, 0.f, 0.f, 0.f, 0.f, 0.f, 0.f, 0.f};
        #pragma unroll
        for (int cc = 0; cc < CCH; ++cc) {
            const int c = ch * CCH + cc;
            float n[9];
            #pragma unroll
            for (int kh = 0; kh < 3; ++kh)
                #pragma unroll
                for (int kw = 0; kw < 3; ++kw)
                    n[kh * 3 + kw] = sx[cc * CPLANE + (ty + kh) * HALO_W + (tx + kw)];
            const float4* wp = (const float4*)(swts + c * 72);
            float a8[8] = {0.f, 0.f, 0.f, 0.f, 0.f, 0.f, 0.f, 0.f};
            #pragma unroll
            for (int k = 0; k < 9; ++k) {          // k-outer: same k-ascending
                const float4 wa = wp[k * 2];        // chains per accumulator
                const float4 wb = wp[k * 2 + 1];    // (bit-identical to R12)
                a8[0] = fmaf(n[k], wa.x, a8[0]);
                a8[1] = fmaf(n[k], wa.y, a8[1]);
                a8[2] = fmaf(n[k], wa.z, a8[2]);
                a8[3] = fmaf(n[k], wa.w, a8[3]);
                a8[4] = fmaf(n[k], wb.x, a8[4]);
                a8[5] = fmaf(n[k], wb.y, a8[5]);
                a8[6] = fmaf(n[k], wb.z, a8[6]);
                a8[7] = fmaf(n[k], wb.w, a8[7]);
            }
            // rg = r*2+g  ->  pg index r + g*4
            pg[0] += a8[0]; pg[4] += a8[1];
            pg[1] += a8[2]; pg[5] += a8[3];
            pg[2] += a8[4]; pg[6] += a8[5];
            pg[3] += a8[6]; pg[7] += a8[7];
        }
        #pragma unroll
        for (int i = 0; i < 8; ++i) ga[i] += pg[i];
    }

    int r1 = 0, r2 = 0;
    {
        float m = ga[0];
        #pragma unroll
        for (int r = 1; r < 4; ++r) if (ga[r] > m) { m = ga[r]; r1 = r; }   // first-max ties
        float m2 = ga[4];
        #pragma unroll
        for (int r = 1; r < 4; ++r) if (ga[4 + r] > m2) { m2 = ga[4 + r]; r2 = r; }
    }

    // --- pass transition: overlay skern+satt into swts (batched) ---
    __syncthreads();
    {
        const float4* k4 = (const float4*)kws;
        const float4 k0 = k4[tid], k1 = k4[tid + 256];
        const float kt = kws[2048 + tid];
        const float at = aws[tid];
        float4* kd4 = (float4*)swts;                  // skern at 0
        kd4[tid] = k0; kd4[tid + 256] = k1;
        swts[2048 + tid] = kt;                        // skern tail
        swts[2304 + tid] = at;                        // satt
    }
    // visibility: pass-2 loop-top barrier

    // ================= PASS 2: depthwise -> bf16 rbuf, K-split GEMM =================
    f32x4 acc[4][4];

#define DW_CHUNK(ch)                                                           \
    do {                                                                       \
        unsigned int us[4] = {0u, 0u, 0u, 0u};                                 \
        _Pragma("unroll")                                                      \
        for (int cc = 0; cc < CCH; ++cc) {                                     \
            const int c = (ch) * CCH + cc;                                     \
            float n[9];                                                        \
            _Pragma("unroll")                                                  \
            for (int kh = 0; kh < 3; ++kh)                                     \
                _Pragma("unroll")                                              \
                for (int kw = 0; kw < 3; ++kw)                                 \
                    n[kh * 3 + kw] = sx[cc * CPLANE + (ty + kh) * HALO_W + (tx + kw)]; \
            float dw = 0.f;                                                    \
            _Pragma("unroll")                                                  \
            for (int k = 0; k < 9; ++k)                                        \
                dw = fmaf(n[k], swts[c * 36 + k * 4 + r1], dw);                \
            const float routed = dw > 0.f ? dw : 0.1f * dw;                    \
            us[cc >> 1] |= rne_bf16(routed) << ((cc & 1) * 16);                \
        }                                                                      \
        const int byteoff = wave * 4096 + lane * 64 +                          \
                            ((((ch) & 3) ^ RSWZ(lane)) << 4);                  \
        *(u32x4*)(rbuf + byteoff) = (u32x4){us[0], us[1], us[2], us[3]};       \
    } while (0)

#define GEMM_HALF(ks)                                                          \
    do {                                                                       \
        const bf16x8* bglob = (const bf16x8*)(wsu + WS_CWB);                   \
        bf16x8 av0, av1, av2, av3;                                             \
        {                                                                      \
            const int sk = lane >> 4;                                          \
            const int p0 = (lane & 15),      p1 = 16 + (lane & 15);            \
            const int p2 = 32 + (lane & 15), p3 = 48 + (lane & 15);            \
            av0 = *(const bf16x8*)(rbuf + wave * 4096 + p0 * 64 + ((sk ^ RSWZ(p0)) << 4)); \
            av1 = *(const bf16x8*)(rbuf + wave * 4096 + p1 * 64 + ((sk ^ RSWZ(p1)) << 4)); \
            av2 = *(const bf16x8*)(rbuf + wave * 4096 + p2 * 64 + ((sk ^ RSWZ(p2)) << 4)); \
            av3 = *(const bf16x8*)(rbuf + wave * 4096 + p3 * 64 + ((sk ^ RSWZ(p3)) << 4)); \
        }                                                                      \
        const bf16x8 bv0 = bglob[(0 * 2 + (ks)) * 64 + lane];                  \
        const bf16x8 bv1 = bglob[(1 * 2 + (ks)) * 64 + lane];                  \
        const bf16x8 bv2 = bglob[(2 * 2 + (ks)) * 64 + lane];                  \
        const bf16x8 bv3 = bglob[(3 * 2 + (ks)) * 64 + lane];                  \
        acc[0][0] = __builtin_amdgcn_mfma_f32_16x16x32_bf16(av0, bv0, acc[0][0], 0, 0, 0); \
        acc[0][1] = __builtin_amdgcn_mfma_f32_16x16x32_bf16(av0, bv1, acc[0][1], 0, 0, 0); \
        acc[0][2] = __builtin_amdgcn_mfma_f32_16x16x32_bf16(av0, bv2, acc[0][2], 0, 0, 0); \
        acc[0][3] = __builtin_amdgcn_mfma_f32_16x16x32_bf16(av0, bv3, acc[0][3], 0, 0, 0); \
        acc[1][0] = __builtin_amdgcn_mfma_f32_16x16x32_bf16(av1, bv0, acc[1][0], 0, 0, 0); \
        acc[1][1] = __builtin_amdgcn_mfma_f32_16x16x32_bf16(av1, bv1, acc[1][1], 0, 0, 0); \
        acc[1][2] = __builtin_amdgcn_mfma_f32_16x16x32_bf16(av1, bv2, acc[1][2], 0, 0, 0); \
        acc[1][3] = __builtin_amdgcn_mfma_f32_16x16x32_bf16(av1, bv3, acc[1][3], 0, 0, 0); \
        acc[2][0] = __builtin_amdgcn_mfma_f32_16x16x32_bf16(av2, bv0, acc[2][0], 0, 0, 0); \
        acc[2][1] = __builtin_amdgcn_mfma_f32_16x16x32_bf16(av2, bv1, acc[2][1], 0, 0, 0); \
        acc[2][2] = __builtin_amdgcn_mfma_f32_16x16x32_bf16(av2, bv2, acc[2][2], 0, 0, 0); \
        acc[2][3] = __builtin_amdgcn_mfma_f32_16x16x32_bf16(av2, bv3, acc[2][3], 0, 0, 0); \
        acc[3][0] = __builtin_amdgcn_mfma_f32_16x16x32_bf16(av3, bv0, acc[3][0], 0, 0, 0); \
        acc[3][1] = __builtin_amdgcn_mfma_f32_16x16x32_bf16(av3, bv1, acc[3][1], 0, 0, 0); \
        acc[3][2] = __builtin_amdgcn_mfma_f32_16x16x32_bf16(av3, bv2, acc[3][2], 0, 0, 0); \
        acc[3][3] = __builtin_amdgcn_mfma_f32_16x16x32_bf16(av3, bv3, acc[3][3], 0, 0, 0); \
    } while (0)

    #pragma unroll 1
    for (int ch = 0; ch < 4; ++ch) {
        __syncthreads();
        STAGE_CHUNK(ch);
        __syncthreads();
        DW_CHUNK(ch);
    }
    #pragma unroll
    for (int mt = 0; mt < 4; ++mt)
        #pragma unroll
        for (int nt = 0; nt < 4; ++nt)
            acc[mt][nt] = (f32x4){0.f, 0.f, 0.f, 0.f};
    GEMM_HALF(0);          // same-wave rbuf write->read: compiler lgkmcnt ordering

    #pragma unroll 1
    for (int ch = 4; ch < 8; ++ch) {
        __syncthreads();
        STAGE_CHUNK(ch);
        __syncthreads();
        DW_CHUNK(ch);
    }
    GEMM_HALF(1);

    __syncthreads();       // all rbuf/sx reads done: pool becomes sy

    // --- epilogue per nt-group: transpose (stride 17, per-wave region) + store ---
    const int hh = h0 + ty;
    const int ww = w0 + tx;
    float* op = out + (size_t)b * Cx * HWx + hh * Wx + ww;
    const float* xp = xb + hh * Wx + ww;
    float* syw = sy + wave * 1088;
    #pragma unroll
    for (int nt = 0; nt < 4; ++nt) {
        #pragma unroll
        for (int mt = 0; mt < 4; ++mt)
            #pragma unroll
            for (int q = 0; q < 4; ++q)
                syw[(mt * 16 + (lane >> 4) * 4 + q) * 17 + (lane & 15)] = acc[mt][nt][q];
        #pragma unroll
        for (int t = 0; t < 16; ++t) {
            const int o = nt * 16 + t;
            const float v = syw[lane * 17 + t] + convb[o]
                          + xp[(size_t)o * HWx] * swts[2304 + o * 4 + r2];
            op[(size_t)o * HWx] = v;
        }
    }
}

extern "C" void kernel_launch(void* const* d_in, const int* in_sizes, int n_in,
                              void* d_out, int out_size, void* d_ws, size_t ws_size,
                              hipStream_t stream) {
    const float* x0     = (const float*)d_in[0];
    const float* x_deg  = (const float*)d_in[1];
    const float* kw1    = (const float*)d_in[2];
    const float* kw2    = (const float*)d_in[3];
    const float* convw  = (const float*)d_in[4];
    const float* convb  = (const float*)d_in[5];
    const float* ca_w1  = (const float*)d_in[6];
    const float* ca_w2  = (const float*)d_in[7];
    const float* g1w    = (const float*)d_in[8];
    const float* g1b    = (const float*)d_in[9];
    const float* g2w    = (const float*)d_in[10];
    const float* g2b    = (const float*)d_in[11];
    float* outp = (float*)d_out;
    float* wsf  = (float*)d_ws;

    da_prep<<<Bx + 1, 256, 0, stream>>>(x_deg, kw1, kw2, convw, ca_w1, ca_w2,
                                        g1w, g2w, wsf);

    dim3 grid(Wx / TW, Hx / TH, Bx);   // 4 x 16 x 16 = 1024 blocks
    da_main<<<grid, 256, 0, stream>>>(x0, wsf, g1b, g2b, convb, outp);
}

// Round 14
// 171.289 us; speedup vs baseline: 2.0598x; 2.0598x over previous
//
#include <hip/hip_runtime.h>
#include <math.h>

#define Bx 16
#define Cx 64
#define Hx 128
#define Wx 128
#define HWx (Hx * Wx)

#define TW 32
#define TH 8
#define CCH 8
#define HALO_W (TW + 2)
#define HALO_H (TH + 2)
#define CPLANE (HALO_H * HALO_W)          // 340
#define CHUNK_ELEMS (CCH * CPLANE)        // 2720
#define NCHUNK (Cx / CCH)                 // 8

// workspace layout (float/u32 offsets)
#define WS_CWB   0                         // 1x1 B-fragments bf16: 8 tiles*64 lanes*4 u32 = 2048
#define WS_GPACK 2048                      // gpack8[c*72 + k*8 + rg]  4608   (rg=r*2+g)
#define WS_KERN  6656                      // per-b [c*36+k*4+g]       16*2304 = 36864
#define WS_ATT   43520                     // per-b [c*4+r]            16*256  = 4096

typedef short bf16x8 __attribute__((ext_vector_type(8)));
typedef float f32x4  __attribute__((ext_vector_type(4)));
typedef unsigned int u32x4 __attribute__((ext_vector_type(4)));

__device__ __host__ inline unsigned rne_bf16(float f) {
    union { float f; unsigned u; } v; v.f = f;
    return (v.u + 0x7fffu + ((v.u >> 16) & 1u)) >> 16;
}

// ---------------- prep: hypernetwork + weight repacking (R13-validated) ----------------
__global__ __launch_bounds__(256)
void da_prep(const float* __restrict__ x_deg,
             const float* __restrict__ kw1,
             const float* __restrict__ kw2,
             const float* __restrict__ convw,
             const float* __restrict__ ca_w1,
             const float* __restrict__ ca_w2,
             const float* __restrict__ g1w,
             const float* __restrict__ g2w,
             float* __restrict__ ws)
{
    const int b = blockIdx.x;
    const int tid = threadIdx.x;
    unsigned int* wsu = (unsigned int*)ws;

    if (b == Bx) {
        // 1x1 weights as MFMA B-fragments, bf16 RNE (R12-validated layout).
        for (int i = tid; i < 2048; i += 256) {
            const int t    = i >> 8;
            const int rem  = i & 255;
            const int lane = rem >> 2;
            const int w    = rem & 3;
            const int nt = t >> 1, ks = t & 1;
            const int o = nt * 16 + (lane & 15);
            const int c = ks * 32 + ((lane >> 4) << 3) + w * 2;
            const unsigned lo = rne_bf16(convw[o * 64 + c]);
            const unsigned hi = rne_bf16(convw[o * 64 + c + 1]);
            wsu[WS_CWB + i] = lo | (hi << 16);
        }
        // guide weights packed [c][k][8rg]: per-k 8 floats = 2 aligned float4
        for (int i = tid; i < 4608; i += 256) {
            const int c = i / 72;
            const int rem = i - c * 72;
            const int k  = rem >> 3;
            const int rg = rem & 7;
            const int r = rg >> 1;
            const int g = rg & 1;
            const float* src = g ? g2w : g1w;
            ws[WS_GPACK + i] = src[(r * Cx + c) * 9 + k];
        }
        return;
    }

    __shared__ float h1[16];
    __shared__ float a1[16];
    if (tid < 32) {
        const int j = tid & 15;
        const float* wsrc = (tid < 16) ? (kw1 + j * Cx) : (ca_w1 + j * Cx);
        float acc = 0.f;
        #pragma unroll 8
        for (int c = 0; c < Cx; ++c) acc = fmaf(x_deg[b * Cx + c], wsrc[c], acc);
        acc = acc > 0.f ? acc : 0.1f * acc;               // leaky_relu 0.1
        if (tid < 16) h1[j] = acc; else a1[j] = acc;
    }
    __syncthreads();

    for (int o4 = tid; o4 < 4 * 576; o4 += 256) {
        const int g = o4 / 576;
        const int o = o4 - g * 576;
        float acc = 0.f;
        #pragma unroll
        for (int i = 0; i < 4; ++i)
            acc = fmaf(h1[g * 4 + i], kw2[(g * 576 + o) * 4 + i], acc);
        const int c = o / 9;
        const int k = o - c * 9;
        ws[WS_KERN + b * 2304 + c * 36 + k * 4 + g] = acc;
    }
    {
        const int r = tid >> 6;
        const int c = tid & 63;
        float acc = 0.f;
        #pragma unroll
        for (int i = 0; i < 4; ++i)
            acc = fmaf(a1[r * 4 + i], ca_w2[(r * Cx + c) * 4 + i], acc);
        ws[WS_ATT + b * 256 + c * 4 + r] = 1.f / (1.f + expf(-acc));
    }
}

// ---------------- main fused kernel: R12 structure + LDS diet (no launch-bounds trap) ----------------
// R13 lesson: __launch_bounds__(256,3) splits the unified file ~84V/84A ->
// VALU live-set spill. So keep (256,2) (R12-proven 92 VGPR clean) and get
// occupancy from LDS alone: gpack halved+staged per 32-ch half (10 KB swts)
// and sy transpose aliased into each wave's PRIVATE rbuf region (-17 KB).
// Total 53,888 B <= 54,613 -> 3 blocks/CU. GEMM/acc/y/epilogue byte-level R12.
__global__ __launch_bounds__(256, 2)
void da_main(const float* __restrict__ x0,
             const float* __restrict__ ws,
             const float* __restrict__ g1b,
             const float* __restrict__ g2b,
             const float* __restrict__ convb,
             float* __restrict__ out)
{
    const int b  = blockIdx.z;
    const int h0 = blockIdx.y * TH;
    const int w0 = blockIdx.x * TW;
    const int tid = threadIdx.x;
    const int tx = tid & (TW - 1);
    const int ty = tid >> 5;
    const int lane = tid & 63;
    const int wave = tid >> 6;

    // swts: pass1 = gpack half [c&31][k][8] (2304 fl); pass2 = skern[0,2304)+satt[2304,2560)
    __shared__ __align__(16) float swts[2560];            // 10.0 KB
    // pool: sx float[2720] | rbuf [wave][64pix][64ch] bf16 (32 KB, wave-private)
    __shared__ __align__(16) char pool[10880 + 32768];    // 42.6 KB
    float* sx = (float*)pool;
    char*  rbuf = pool + 10880;
    // total 53,888 B -> 3 blocks/CU by LDS

    const float* xb  = x0 + (size_t)b * Cx * HWx;
    const float* kws = ws + WS_KERN + b * 2304;
    const float* aws = ws + WS_ATT  + b * 256;
    const unsigned int* wsu = (const unsigned int*)ws;

    // --- per-thread staging offsets, computed ONCE (named ints, no array) ---
    int o0, o1, o2, o3, o4, o5, o6, o7, o8, o9, o10;
    unsigned vmask = 0u;
#define MKOFF(i, oname)                                                        \
    do {                                                                       \
        const int e   = tid + (i) * 256;                                       \
        const int cc  = e / CPLANE;                                            \
        const int rem = e - cc * CPLANE;                                       \
        const int row = rem / HALO_W;                                          \
        const int col = rem - row * HALO_W;                                    \
        const int gh  = h0 - 1 + row;                                          \
        const int gw  = w0 - 1 + col;                                          \
        oname = cc * HWx + gh * Wx + gw;                                       \
        if (e < CHUNK_ELEMS && (unsigned)gh < Hx && (unsigned)gw < Wx)         \
            vmask |= (1u << (i));                                              \
    } while (0)
    MKOFF(0, o0);  MKOFF(1, o1);  MKOFF(2, o2);  MKOFF(3, o3);
    MKOFF(4, o4);  MKOFF(5, o5);  MKOFF(6, o6);  MKOFF(7, o7);
    MKOFF(8, o8);  MKOFF(9, o9);  MKOFF(10, o10);
#undef MKOFF

    // batched staging: issue all loads, then all LDS writes (R10-proven)
#define STAGE_CHUNK(ch)                                                        \
    do {                                                                       \
        const float* src = xb + (size_t)(ch) * CCH * HWx;                      \
        float v0 = 0.f, v1 = 0.f, v2 = 0.f, v3 = 0.f, v4 = 0.f, v5 = 0.f;     \
        float v6 = 0.f, v7 = 0.f, v8 = 0.f, v9 = 0.f, v10 = 0.f;              \
        if (vmask & 1u)      v0  = src[o0];                                    \
        if (vmask & 2u)      v1  = src[o1];                                    \
        if (vmask & 4u)      v2  = src[o2];                                    \
        if (vmask & 8u)      v3  = src[o3];                                    \
        if (vmask & 16u)     v4  = src[o4];                                    \
        if (vmask & 32u)     v5  = src[o5];                                    \
        if (vmask & 64u)     v6  = src[o6];                                    \
        if (vmask & 128u)    v7  = src[o7];                                    \
        if (vmask & 256u)    v8  = src[o8];                                    \
        if (vmask & 512u)    v9  = src[o9];                                    \
        if (vmask & 1024u)   v10 = src[o10];                                   \
        sx[tid]           = v0;   sx[tid + 256]  = v1;                         \
        sx[tid + 512]     = v2;   sx[tid + 768]  = v3;                         \
        sx[tid + 1024]    = v4;   sx[tid + 1280] = v5;                         \
        sx[tid + 1536]    = v6;   sx[tid + 1792] = v7;                         \
        sx[tid + 2048]    = v8;   sx[tid + 2304] = v9;                         \
        if (tid < CHUNK_ELEMS - 2560) sx[tid + 2560] = v10;                    \
    } while (0)

    // gpack half stage: 576 float4, batched
#define STAGE_GPACK(halfbase)                                                  \
    do {                                                                       \
        const float4* s4 = (const float4*)(ws + WS_GPACK + (halfbase));       \
        float4* d4 = (float4*)swts;                                            \
        const float4 g0 = s4[tid];                                             \
        const float4 g1 = s4[tid + 256];                                       \
        float4 g2;                                                             \
        if (tid < 64) g2 = s4[tid + 512];                                      \
        d4[tid] = g0; d4[tid + 256] = g1;                                      \
        if (tid < 64) d4[tid + 512] = g2;                                      \
    } while (0)

    // --- prologue: gpack half 0 (channels 0..31) ---
    STAGE_GPACK(0);

    // ================= PASS 1: guide convs -> argmax =================
    float ga[8];
    #pragma unroll
    for (int r = 0; r < 4; ++r) { ga[r] = g1b[r]; ga[4 + r] = g2b[r]; }

    #pragma unroll 1
    for (int ch = 0; ch < NCHUNK; ++ch) {
        __syncthreads();
        STAGE_CHUNK(ch);
        if (ch == 4) STAGE_GPACK(2304);   // channels 32..63 (chunk-3 reads done)
        __syncthreads();

        float pg[8] = {0.f, 0.f, 0.f, 0.f, 0.f, 0.f, 0.f, 0.f};
        #pragma unroll
        for (int cc = 0; cc < CCH; ++cc) {
            const int c = ch * CCH + cc;
            float n[9];
            #pragma unroll
            for (int kh = 0; kh < 3; ++kh)
                #pragma unroll
                for (int kw = 0; kw < 3; ++kw)
                    n[kh * 3 + kw] = sx[cc * CPLANE + (ty + kh) * HALO_W + (tx + kw)];
            const float4* wp = (const float4*)(swts + (c & 31) * 72);
            float a8[8] = {0.f, 0.f, 0.f, 0.f, 0.f, 0.f, 0.f, 0.f};
            #pragma unroll
            for (int k = 0; k < 9; ++k) {          // k-outer, k-ascending chains
                const float4 wa = wp[k * 2];        // per accumulator:
                const float4 wb = wp[k * 2 + 1];    // bit-identical (R13-validated)
                a8[0] = fmaf(n[k], wa.x, a8[0]);
                a8[1] = fmaf(n[k], wa.y, a8[1]);
                a8[2] = fmaf(n[k], wa.z, a8[2]);
                a8[3] = fmaf(n[k], wa.w, a8[3]);
                a8[4] = fmaf(n[k], wb.x, a8[4]);
                a8[5] = fmaf(n[k], wb.y, a8[5]);
                a8[6] = fmaf(n[k], wb.z, a8[6]);
                a8[7] = fmaf(n[k], wb.w, a8[7]);
            }
            // rg = r*2+g  ->  pg index r + g*4
            pg[0] += a8[0]; pg[4] += a8[1];
            pg[1] += a8[2]; pg[5] += a8[3];
            pg[2] += a8[4]; pg[6] += a8[5];
            pg[3] += a8[6]; pg[7] += a8[7];
        }
        #pragma unroll
        for (int i = 0; i < 8; ++i) ga[i] += pg[i];
    }

    int r1 = 0, r2 = 0;
    {
        float m = ga[0];
        #pragma unroll
        for (int r = 1; r < 4; ++r) if (ga[r] > m) { m = ga[r]; r1 = r; }   // first-max ties
        float m2 = ga[4];
        #pragma unroll
        for (int r = 1; r < 4; ++r) if (ga[4 + r] > m2) { m2 = ga[4 + r]; r2 = r; }
    }

    // --- pass transition: overlay skern+satt into swts (batched) ---
    __syncthreads();
    {
        const float4* k4 = (const float4*)kws;
        const float4 k0 = k4[tid], k1 = k4[tid + 256];
        const float kt = kws[2048 + tid];
        const float at = aws[tid];
        float4* kd4 = (float4*)swts;                  // skern at 0
        kd4[tid] = k0; kd4[tid + 256] = k1;
        swts[2048 + tid] = kt;                        // skern tail
        swts[2304 + tid] = at;                        // satt
    }
    // visibility: pass-2 loop-top barrier

    // ================= PASS 2: routed depthwise -> bf16 rbuf (R12) =================
    #pragma unroll 1
    for (int ch = 0; ch < NCHUNK; ++ch) {
        __syncthreads();
        STAGE_CHUNK(ch);
        __syncthreads();

        unsigned int us[4] = {0u, 0u, 0u, 0u};
        #pragma unroll
        for (int cc = 0; cc < CCH; ++cc) {
            const int c = ch * CCH + cc;
            float n[9];
            #pragma unroll
            for (int kh = 0; kh < 3; ++kh)
                #pragma unroll
                for (int kw = 0; kw < 3; ++kw)
                    n[kh * 3 + kw] = sx[cc * CPLANE + (ty + kh) * HALO_W + (tx + kw)];

            float dw = 0.f;
            #pragma unroll
            for (int k = 0; k < 9; ++k)
                dw = fmaf(n[k], swts[c * 36 + k * 4 + r1], dw);
            const float routed = dw > 0.f ? dw : 0.1f * dw;

            us[cc >> 1] |= rne_bf16(routed) << ((cc & 1) * 16);   // static idx
        }
        {   // one swizzled b128 write into wave-private region (R12 layout)
            const int byteoff = wave * 8192 + lane * 128 + ((ch * 16) ^ ((lane & 7) << 4));
            *(u32x4*)(rbuf + byteoff) = (u32x4){us[0], us[1], us[2], us[3]};
        }
    }
    // no barrier needed: rbuf is wave-private; sx reads finished inside the loop

    // ================= GEMM: Y[64pix][64o] = R * W  (per wave, R12) =================
    float y[Cx];
    {
        f32x4 acc[4][4];
        #pragma unroll
        for (int mt = 0; mt < 4; ++mt)
            #pragma unroll
            for (int nt = 0; nt < 4; ++nt)
                acc[mt][nt] = (f32x4){0.f, 0.f, 0.f, 0.f};

        const bf16x8* bglob = (const bf16x8*)(wsu + WS_CWB);
        #pragma unroll
        for (int ks = 0; ks < 2; ++ks) {
            bf16x8 av[4];
            #pragma unroll
            for (int mt = 0; mt < 4; ++mt) {
                const int pix = mt * 16 + (lane & 15);
                const int byteoff = wave * 8192 + pix * 128 +
                    ((ks * 64 + ((lane >> 4) * 16)) ^ ((pix & 7) << 4));
                av[mt] = *(const bf16x8*)(rbuf + byteoff);
            }
            bf16x8 bv[4];
            #pragma unroll
            for (int nt = 0; nt < 4; ++nt)
                bv[nt] = bglob[(nt * 2 + ks) * 64 + lane];
            #pragma unroll
            for (int mt = 0; mt < 4; ++mt)
                #pragma unroll
                for (int nt = 0; nt < 4; ++nt)
                    acc[mt][nt] = __builtin_amdgcn_mfma_f32_16x16x32_bf16(
                        av[mt], bv[nt], acc[mt][nt], 0, 0, 0);
        }

        // redistribute via padded transpose in the wave's OWN rbuf region
        // (all rbuf reads precede these writes in program order; same-wave
        // DS ops are in-order and compiler cannot prove no-alias to reorder)
        float* syw = (float*)(rbuf + wave * 8192);    // 1088 floats < 8192 B
        #pragma unroll
        for (int nt = 0; nt < 4; ++nt) {
            #pragma unroll
            for (int mt = 0; mt < 4; ++mt)
                #pragma unroll
                for (int q = 0; q < 4; ++q)
                    syw[(mt * 16 + (lane >> 4) * 4 + q) * 17 + (lane & 15)] = acc[mt][nt][q];
            #pragma unroll
            for (int t = 0; t < 16; ++t)
                y[nt * 16 + t] = syw[lane * 17 + t];
        }
    }

    // --- epilogue: bias + CA branch (x center re-read) + store (R12) ---
    const int hh = h0 + ty;
    const int ww = w0 + tx;
    float* op = out + (size_t)b * Cx * HWx + hh * Wx + ww;
    const float* xp = xb + hh * Wx + ww;
    #pragma unroll
    for (int o = 0; o < Cx; ++o) {
        const float v = y[o] + convb[o] + xp[(size_t)o * HWx] * swts[2304 + o * 4 + r2];
        op[(size_t)o * HWx] = v;
    }
}

extern "C" void kernel_launch(void* const* d_in, const int* in_sizes, int n_in,
                              void* d_out, int out_size, void* d_ws, size_t ws_size,
                              hipStream_t stream) {
    const float* x0     = (const float*)d_in[0];
    const float* x_deg  = (const float*)d_in[1];
    const float* kw1    = (const float*)d_in[2];
    const float* kw2    = (const float*)d_in[3];
    const float* convw  = (const float*)d_in[4];
    const float* convb  = (const float*)d_in[5];
    const float* ca_w1  = (const float*)d_in[6];
    const float* ca_w2  = (const float*)d_in[7];
    const float* g1w    = (const float*)d_in[8];
    const float* g1b    = (const float*)d_in[9];
    const float* g2w    = (const float*)d_in[10];
    const float* g2b    = (const float*)d_in[11];
    float* outp = (float*)d_out;
    float* wsf  = (float*)d_ws;

    da_prep<<<Bx + 1, 256, 0, stream>>>(x_deg, kw1, kw2, convw, ca_w1, ca_w2,
                                        g1w, g2w, wsf);

    dim3 grid(Wx / TW, Hx / TH, Bx);   // 4 x 16 x 16 = 1024 blocks
    da_main<<<grid, 256, 0, stream>>>(x0, wsf, g1b, g2b, convb, outp);
}

// Round 15
// 146.308 us; speedup vs baseline: 2.4115x; 1.1707x over previous
//
#include <hip/hip_runtime.h>
#include <math.h>

#define Bx 16
#define Cx 64
#define Hx 128
#define Wx 128
#define HWx (Hx * Wx)

#define TW 32
#define TH 8
#define CCH 8
#define HALO_W (TW + 2)
#define HALO_H (TH + 2)
#define CPLANE (HALO_H * HALO_W)          // 340
#define CHUNK_ELEMS (CCH * CPLANE)        // 2720
#define NCHUNK (Cx / CCH)                 // 8

// workspace layout (float/u32 offsets) — R12 layout
#define WS_CWB   0                         // 1x1 B-fragments bf16: 2048 u32
#define WS_GPACK 2048                      // gpack12[c*96+rg*12+k]  6144  (rg=r*2+g)
#define WS_KERN  8192                      // per-b [c*36+k*4+g]     16*2304
#define WS_ATT   45056                     // per-b [c*4+r]          16*256

typedef short bf16x8 __attribute__((ext_vector_type(8)));
typedef float f32x4  __attribute__((ext_vector_type(4)));
typedef unsigned int u32x4 __attribute__((ext_vector_type(4)));

__device__ __host__ inline unsigned rne_bf16(float f) {
    union { float f; unsigned u; } v; v.f = f;
    return (v.u + 0x7fffu + ((v.u >> 16) & 1u)) >> 16;
}

// rbuf row swizzle: 4 slots of 16B per 64B pixel row (R13-validated)
#define RSWZ(p) ((((p) & 3) ^ (((p) >> 2) & 3)))

// ---------------- prep: hypernetwork + weight repacking (R12 verbatim) ----------------
__global__ __launch_bounds__(256)
void da_prep(const float* __restrict__ x_deg,
             const float* __restrict__ kw1,
             const float* __restrict__ kw2,
             const float* __restrict__ convw,
             const float* __restrict__ ca_w1,
             const float* __restrict__ ca_w2,
             const float* __restrict__ g1w,
             const float* __restrict__ g2w,
             float* __restrict__ ws)
{
    const int b = blockIdx.x;
    const int tid = threadIdx.x;
    unsigned int* wsu = (unsigned int*)ws;

    if (b == Bx) {
        // 1x1 weights as MFMA B-fragments, bf16 RNE (R12-validated layout).
        for (int i = tid; i < 2048; i += 256) {
            const int t    = i >> 8;
            const int rem  = i & 255;
            const int lane = rem >> 2;
            const int w    = rem & 3;
            const int nt = t >> 1, ks = t & 1;
            const int o = nt * 16 + (lane & 15);
            const int c = ks * 32 + ((lane >> 4) << 3) + w * 2;
            const unsigned lo = rne_bf16(convw[o * 64 + c]);
            const unsigned hi = rne_bf16(convw[o * 64 + c + 1]);
            wsu[WS_CWB + i] = lo | (hi << 16);
        }
        for (int i = tid; i < 6144; i += 256) {           // gpack12[c][rg=r*2+g][12]
            const int c = i / 96;
            int rem = i - c * 96;
            const int rg = rem / 12;
            const int k  = rem - rg * 12;
            const int r = rg >> 1;
            const int g = rg & 1;
            const float* src = g ? g2w : g1w;
            ws[WS_GPACK + i] = (k < 9) ? src[(r * Cx + c) * 9 + k] : 0.f;
        }
        return;
    }

    __shared__ float h1[16];
    __shared__ float a1[16];
    if (tid < 32) {
        const int j = tid & 15;
        const float* wsrc = (tid < 16) ? (kw1 + j * Cx) : (ca_w1 + j * Cx);
        float acc = 0.f;
        #pragma unroll 8
        for (int c = 0; c < Cx; ++c) acc = fmaf(x_deg[b * Cx + c], wsrc[c], acc);
        acc = acc > 0.f ? acc : 0.1f * acc;               // leaky_relu 0.1
        if (tid < 16) h1[j] = acc; else a1[j] = acc;
    }
    __syncthreads();

    for (int o4 = tid; o4 < 4 * 576; o4 += 256) {
        const int g = o4 / 576;
        const int o = o4 - g * 576;
        float acc = 0.f;
        #pragma unroll
        for (int i = 0; i < 4; ++i)
            acc = fmaf(h1[g * 4 + i], kw2[(g * 576 + o) * 4 + i], acc);
        const int c = o / 9;
        const int k = o - c * 9;
        ws[WS_KERN + b * 2304 + c * 36 + k * 4 + g] = acc;
    }
    {
        const int r = tid >> 6;
        const int c = tid & 63;
        float acc = 0.f;
        #pragma unroll
        for (int i = 0; i < 4; ++i)
            acc = fmaf(a1[r * 4 + i], ca_w2[(r * Cx + c) * 4 + i], acc);
        ws[WS_ATT + b * 256 + c * 4 + r] = 1.f / (1.f + expf(-acc));
    }
}

// ---------------- main: R12 body + R13 K-split GEMM + LDS 53.9 KB -> 3 blocks/CU ----------------
// Budgets for 3 blocks/CU: LDS <= 54,613 (26,624+27,264 = 53,888 OK) and
// VGPR <= ~106 (+64 AGPR = 170). R12's body proved 92 VGPR; R14's 128-VGPR
// blowup came from mid-loop conditional weight staging (removed here).
// NO __launch_bounds__ occupancy request (R13 lesson: it splits the unified
// file and spills the VALU set). Argmax path bit-identical to R12.
__global__ __launch_bounds__(256, 2)
void da_main(const float* __restrict__ x0,
             const float* __restrict__ ws,
             const float* __restrict__ g1b,
             const float* __restrict__ g2b,
             const float* __restrict__ convb,
             float* __restrict__ out)
{
    const int b  = blockIdx.z;
    const int h0 = blockIdx.y * TH;
    const int w0 = blockIdx.x * TW;
    const int tid = threadIdx.x;
    const int tx = tid & (TW - 1);
    const int ty = tid >> 5;
    const int lane = tid & 63;
    const int wave = tid >> 6;

    // swts: pass1 = gpack12 [c][rg][12] (6144 fl); pass2 = skern[0,2304)+satt[2304,2560)
    __shared__ __align__(16) float swts[6656];            // 26,624 B
    // pool: sx float[2720] @0 | rbuf [wave][64pix][32ch] bf16 @10880 (16 KB)
    // after GEMM: whole pool dead -> sy transpose (4 x 1088 fl)
    __shared__ __align__(16) char pool[27264];
    float* sx = (float*)pool;
    char*  rbuf = pool + 10880;
    // total 53,888 B -> 3 blocks/CU by LDS

    const float* xb  = x0 + (size_t)b * Cx * HWx;
    const float* kws = ws + WS_KERN + b * 2304;
    const float* aws = ws + WS_ATT  + b * 256;
    const unsigned int* wsu = (const unsigned int*)ws;

    // --- per-thread staging offsets, computed ONCE (named ints, no array) ---
    int o0, o1, o2, o3, o4, o5, o6, o7, o8, o9, o10;
    unsigned vmask = 0u;
#define MKOFF(i, oname)                                                        \
    do {                                                                       \
        const int e   = tid + (i) * 256;                                       \
        const int cc  = e / CPLANE;                                            \
        const int rem = e - cc * CPLANE;                                       \
        const int row = rem / HALO_W;                                          \
        const int col = rem - row * HALO_W;                                    \
        const int gh  = h0 - 1 + row;                                          \
        const int gw  = w0 - 1 + col;                                          \
        oname = cc * HWx + gh * Wx + gw;                                       \
        if (e < CHUNK_ELEMS && (unsigned)gh < Hx && (unsigned)gw < Wx)         \
            vmask |= (1u << (i));                                              \
    } while (0)
    MKOFF(0, o0);  MKOFF(1, o1);  MKOFF(2, o2);  MKOFF(3, o3);
    MKOFF(4, o4);  MKOFF(5, o5);  MKOFF(6, o6);  MKOFF(7, o7);
    MKOFF(8, o8);  MKOFF(9, o9);  MKOFF(10, o10);
#undef MKOFF

    // batched staging: issue all loads, then all LDS writes (R10-proven)
#define STAGE_CHUNK(ch)                                                        \
    do {                                                                       \
        const float* src = xb + (size_t)(ch) * CCH * HWx;                      \
        float v0 = 0.f, v1 = 0.f, v2 = 0.f, v3 = 0.f, v4 = 0.f, v5 = 0.f;     \
        float v6 = 0.f, v7 = 0.f, v8 = 0.f, v9 = 0.f, v10 = 0.f;              \
        if (vmask & 1u)      v0  = src[o0];                                    \
        if (vmask & 2u)      v1  = src[o1];                                    \
        if (vmask & 4u)      v2  = src[o2];                                    \
        if (vmask & 8u)      v3  = src[o3];                                    \
        if (vmask & 16u)     v4  = src[o4];                                    \
        if (vmask & 32u)     v5  = src[o5];                                    \
        if (vmask & 64u)     v6  = src[o6];                                    \
        if (vmask & 128u)    v7  = src[o7];                                    \
        if (vmask & 256u)    v8  = src[o8];                                    \
        if (vmask & 512u)    v9  = src[o9];                                    \
        if (vmask & 1024u)   v10 = src[o10];                                   \
        sx[tid]           = v0;   sx[tid + 256]  = v1;                         \
        sx[tid + 512]     = v2;   sx[tid + 768]  = v3;                         \
        sx[tid + 1024]    = v4;   sx[tid + 1280] = v5;                         \
        sx[tid + 1536]    = v6;   sx[tid + 1792] = v7;                         \
        sx[tid + 2048]    = v8;   sx[tid + 2304] = v9;                         \
        if (tid < CHUNK_ELEMS - 2560) sx[tid + 2560] = v10;                    \
    } while (0)

    // --- prologue: full gpack12 (1536 float4) batched into LDS (R12) ---
    {
        const float4* s4 = (const float4*)(ws + WS_GPACK);
        float4* d4 = (float4*)swts;
        const float4 g0 = s4[tid], g1 = s4[tid + 256], g2 = s4[tid + 512];
        const float4 g3 = s4[tid + 768], g4 = s4[tid + 1024], g5 = s4[tid + 1280];
        d4[tid] = g0; d4[tid + 256] = g1; d4[tid + 512] = g2;
        d4[tid + 768] = g3; d4[tid + 1024] = g4; d4[tid + 1280] = g5;
    }

    // ================= PASS 1: guide convs -> argmax (R12 verbatim) =================
    float ga[8];
    #pragma unroll
    for (int r = 0; r < 4; ++r) { ga[r] = g1b[r]; ga[4 + r] = g2b[r]; }

    #pragma unroll 1
    for (int ch = 0; ch < NCHUNK; ++ch) {
        __syncthreads();
        STAGE_CHUNK(ch);
        __syncthreads();

        float pg[8] = {0.f, 0.f, 0.f, 0.f, 0.f, 0.f, 0.f, 0.f};
        #pragma unroll
        for (int cc = 0; cc < CCH; ++cc) {
            const int c = ch * CCH + cc;
            float n[9];
            #pragma unroll
            for (int kh = 0; kh < 3; ++kh)
                #pragma unroll
                for (int kw = 0; kw < 3; ++kw)
                    n[kh * 3 + kw] = sx[cc * CPLANE + (ty + kh) * HALO_W + (tx + kw)];
            const float4* gpv = (const float4*)(swts + c * 96);  // uniform b128 broadcast
            #pragma unroll
            for (int rg = 0; rg < 8; ++rg) {
                const float4 q0 = gpv[rg * 3 + 0];
                const float4 q1 = gpv[rg * 3 + 1];
                const float4 q2 = gpv[rg * 3 + 2];
                float s = 0.f;                        // k-ascending, bit-identical chain
                s = fmaf(n[0], q0.x, s); s = fmaf(n[1], q0.y, s); s = fmaf(n[2], q0.z, s);
                s = fmaf(n[3], q0.w, s); s = fmaf(n[4], q1.x, s); s = fmaf(n[5], q1.y, s);
                s = fmaf(n[6], q1.z, s); s = fmaf(n[7], q1.w, s); s = fmaf(n[8], q2.x, s);
                pg[(rg >> 1) + (rg & 1) * 4] += s;
            }
        }
        #pragma unroll
        for (int i = 0; i < 8; ++i) ga[i] += pg[i];
    }

    int r1 = 0, r2 = 0;
    {
        float m = ga[0];
        #pragma unroll
        for (int r = 1; r < 4; ++r) if (ga[r] > m) { m = ga[r]; r1 = r; }   // first-max ties
        float m2 = ga[4];
        #pragma unroll
        for (int r = 1; r < 4; ++r) if (ga[4 + r] > m2) { m2 = ga[4 + r]; r2 = r; }
    }

    // --- pass transition: overlay skern+satt into swts (batched, R12) ---
    __syncthreads();
    {
        const float4* k4 = (const float4*)kws;
        const float4 k0 = k4[tid], k1 = k4[tid + 256];
        const float kt = kws[2048 + tid];
        const float at = aws[tid];
        float4* kd4 = (float4*)swts;                  // skern at 0
        kd4[tid] = k0; kd4[tid + 256] = k1;
        swts[2048 + tid] = kt;                        // skern tail
        swts[2304 + tid] = at;                        // satt
    }
    // visibility: pass-2 loop-top barrier

    // ================= PASS 2: depthwise -> bf16 rbuf, K-split GEMM (R13) =================
#define DW_CHUNK(ch)                                                           \
    do {                                                                       \
        unsigned int us[4] = {0u, 0u, 0u, 0u};                                 \
        _Pragma("unroll")                                                      \
        for (int cc = 0; cc < CCH; ++cc) {                                     \
            const int c = (ch) * CCH + cc;                                     \
            float n[9];                                                        \
            _Pragma("unroll")                                                  \
            for (int kh = 0; kh < 3; ++kh)                                     \
                _Pragma("unroll")                                              \
                for (int kw = 0; kw < 3; ++kw)                                 \
                    n[kh * 3 + kw] = sx[cc * CPLANE + (ty + kh) * HALO_W + (tx + kw)]; \
            float dw = 0.f;                                                    \
            _Pragma("unroll")                                                  \
            for (int k = 0; k < 9; ++k)                                        \
                dw = fmaf(n[k], swts[c * 36 + k * 4 + r1], dw);                \
            const float routed = dw > 0.f ? dw : 0.1f * dw;                    \
            us[cc >> 1] |= rne_bf16(routed) << ((cc & 1) * 16);                \
        }                                                                      \
        const int byteoff = wave * 4096 + lane * 64 +                          \
                            ((((ch) & 3) ^ RSWZ(lane)) << 4);                  \
        *(u32x4*)(rbuf + byteoff) = (u32x4){us[0], us[1], us[2], us[3]};       \
    } while (0)

    f32x4 acc[4][4];

#define GEMM_HALF(ks)                                                          \
    do {                                                                       \
        const bf16x8* bglob = (const bf16x8*)(wsu + WS_CWB);                   \
        bf16x8 av[4];                                                          \
        _Pragma("unroll")                                                      \
        for (int mt = 0; mt < 4; ++mt) {                                       \
            const int pix = mt * 16 + (lane & 15);                             \
            const int sk = lane >> 4;                                          \
            av[mt] = *(const bf16x8*)(rbuf + wave * 4096 + pix * 64 +          \
                                      ((sk ^ RSWZ(pix)) << 4));                \
        }                                                                      \
        bf16x8 bv[4];                                                          \
        _Pragma("unroll")                                                      \
        for (int nt = 0; nt < 4; ++nt)                                         \
            bv[nt] = bglob[(nt * 2 + (ks)) * 64 + lane];                       \
        _Pragma("unroll")                                                      \
        for (int mt = 0; mt < 4; ++mt)                                         \
            _Pragma("unroll")                                                  \
            for (int nt = 0; nt < 4; ++nt)                                     \
                acc[mt][nt] = __builtin_amdgcn_mfma_f32_16x16x32_bf16(         \
                    av[mt], bv[nt], acc[mt][nt], 0, 0, 0);                     \
    } while (0)

    #pragma unroll 1
    for (int ch = 0; ch < 4; ++ch) {
        __syncthreads();
        STAGE_CHUNK(ch);
        __syncthreads();
        DW_CHUNK(ch);
    }
    #pragma unroll
    for (int mt = 0; mt < 4; ++mt)
        #pragma unroll
        for (int nt = 0; nt < 4; ++nt)
            acc[mt][nt] = (f32x4){0.f, 0.f, 0.f, 0.f};
    GEMM_HALF(0);          // same-wave rbuf write->read: in-order DS

    #pragma unroll 1
    for (int ch = 4; ch < 8; ++ch) {
        __syncthreads();
        STAGE_CHUNK(ch);
        __syncthreads();
        DW_CHUNK(ch);
    }
    GEMM_HALF(1);

    __syncthreads();       // all sx/rbuf reads done: pool becomes sy

    // --- epilogue per nt-group: padded transpose + store (R13-validated) ---
    const int hh = h0 + ty;
    const int ww = w0 + tx;
    float* op = out + (size_t)b * Cx * HWx + hh * Wx + ww;
    const float* xp = xb + hh * Wx + ww;
    float* syw = (float*)pool + wave * 1088;
    #pragma unroll
    for (int nt = 0; nt < 4; ++nt) {
        #pragma unroll
        for (int mt = 0; mt < 4; ++mt)
            #pragma unroll
            for (int q = 0; q < 4; ++q)
                syw[(mt * 16 + (lane >> 4) * 4 + q) * 17 + (lane & 15)] = acc[mt][nt][q];
        #pragma unroll
        for (int t = 0; t < 16; ++t) {
            const int o = nt * 16 + t;
            const float v = syw[lane * 17 + t] + convb[o]
                          + xp[(size_t)o * HWx] * swts[2304 + o * 4 + r2];
            op[(size_t)o * HWx] = v;
        }
    }
}

extern "C" void kernel_launch(void* const* d_in, const int* in_sizes, int n_in,
                              void* d_out, int out_size, void* d_ws, size_t ws_size,
                              hipStream_t stream) {
    const float* x0     = (const float*)d_in[0];
    const float* x_deg  = (const float*)d_in[1];
    const float* kw1    = (const float*)d_in[2];
    const float* kw2    = (const float*)d_in[3];
    const float* convw  = (const float*)d_in[4];
    const float* convb  = (const float*)d_in[5];
    const float* ca_w1  = (const float*)d_in[6];
    const float* ca_w2  = (const float*)d_in[7];
    const float* g1w    = (const float*)d_in[8];
    const float* g1b    = (const float*)d_in[9];
    const float* g2w    = (const float*)d_in[10];
    const float* g2b    = (const float*)d_in[11];
    float* outp = (float*)d_out;
    float* wsf  = (float*)d_ws;

    da_prep<<<Bx + 1, 256, 0, stream>>>(x_deg, kw1, kw2, convw, ca_w1, ca_w2,
                                        g1w, g2w, wsf);

    dim3 grid(Wx / TW, Hx / TH, Bx);   // 4 x 16 x 16 = 1024 blocks
    da_main<<<grid, 256, 0, stream>>>(x0, wsf, g1b, g2b, convb, outp);
}

// Round 17
// 126.271 us; speedup vs baseline: 2.7941x; 1.1587x over previous
//
#include <hip/hip_runtime.h>
#include <math.h>

#define Bx 16
#define Cx 64
#define Hx 128
#define Wx 128
#define HWx (Hx * Wx)

#define TW 32
#define TH 8
#define CCH 8
#define HALO_W (TW + 2)
#define HALO_H (TH + 2)
#define CPLANE (HALO_H * HALO_W)          // 340
#define CHUNK_ELEMS (CCH * CPLANE)        // 2720
#define NCHUNK (Cx / CCH)                 // 8

// workspace layout (float/u32 offsets) — R13 layout (gpack8)
#define WS_CWB   0                         // 1x1 B-fragments bf16: 2048 u32
#define WS_GPACK 2048                      // gpack8[c*72 + k*8 + rg]  4608  (rg=r*2+g)
#define WS_KERN  6656                      // per-b [c*36+k*4+g]       16*2304
#define WS_ATT   43520                     // per-b [c*4+r]            16*256

typedef short bf16x8 __attribute__((ext_vector_type(8)));
typedef float f32x4  __attribute__((ext_vector_type(4)));
typedef float f32x2  __attribute__((ext_vector_type(2)));
typedef unsigned int u32x4 __attribute__((ext_vector_type(4)));

__device__ __host__ inline unsigned rne_bf16(float f) {
    union { float f; unsigned u; } v; v.f = f;
    return (v.u + 0x7fffu + ((v.u >> 16) & 1u)) >> 16;
}

// rbuf row swizzle: 4 slots of 16B per 64B pixel row (R13-validated)
#define RSWZ(p) ((((p) & 3) ^ (((p) >> 2) & 3)))

// ---------------- prep: hypernetwork + weight repacking (R13-validated) ----------------
__global__ __launch_bounds__(256)
void da_prep(const float* __restrict__ x_deg,
             const float* __restrict__ kw1,
             const float* __restrict__ kw2,
             const float* __restrict__ convw,
             const float* __restrict__ ca_w1,
             const float* __restrict__ ca_w2,
             const float* __restrict__ g1w,
             const float* __restrict__ g2w,
             float* __restrict__ ws)
{
    const int b = blockIdx.x;
    const int tid = threadIdx.x;
    unsigned int* wsu = (unsigned int*)ws;

    if (b == Bx) {
        // 1x1 weights as MFMA B-fragments, bf16 RNE (R12-validated layout).
        for (int i = tid; i < 2048; i += 256) {
            const int t    = i >> 8;
            const int rem  = i & 255;
            const int lane = rem >> 2;
            const int w    = rem & 3;
            const int nt = t >> 1, ks = t & 1;
            const int o = nt * 16 + (lane & 15);
            const int c = ks * 32 + ((lane >> 4) << 3) + w * 2;
            const unsigned lo = rne_bf16(convw[o * 64 + c]);
            const unsigned hi = rne_bf16(convw[o * 64 + c + 1]);
            wsu[WS_CWB + i] = lo | (hi << 16);
        }
        // guide weights packed [c][k][8rg]: rg adjacent -> float2 pairs
        for (int i = tid; i < 4608; i += 256) {
            const int c = i / 72;
            const int rem = i - c * 72;
            const int k  = rem >> 3;
            const int rg = rem & 7;
            const int r = rg >> 1;
            const int g = rg & 1;
            const float* src = g ? g2w : g1w;
            ws[WS_GPACK + i] = src[(r * Cx + c) * 9 + k];
        }
        return;
    }

    __shared__ float h1[16];
    __shared__ float a1[16];
    if (tid < 32) {
        const int j = tid & 15;
        const float* wsrc = (tid < 16) ? (kw1 + j * Cx) : (ca_w1 + j * Cx);
        float acc = 0.f;
        #pragma unroll 8
        for (int c = 0; c < Cx; ++c) acc = fmaf(x_deg[b * Cx + c], wsrc[c], acc);
        acc = acc > 0.f ? acc : 0.1f * acc;               // leaky_relu 0.1
        if (tid < 16) h1[j] = acc; else a1[j] = acc;
    }
    __syncthreads();

    for (int o4 = tid; o4 < 4 * 576; o4 += 256) {
        const int g = o4 / 576;
        const int o = o4 - g * 576;
        float acc = 0.f;
        #pragma unroll
        for (int i = 0; i < 4; ++i)
            acc = fmaf(h1[g * 4 + i], kw2[(g * 576 + o) * 4 + i], acc);
        const int c = o / 9;
        const int k = o - c * 9;
        ws[WS_KERN + b * 2304 + c * 36 + k * 4 + g] = acc;
    }
    {
        const int r = tid >> 6;
        const int c = tid & 63;
        float acc = 0.f;
        #pragma unroll
        for (int i = 0; i < 4; ++i)
            acc = fmaf(a1[r * 4 + i], ca_w2[(r * Cx + c) * 4 + i], acc);
        ws[WS_ATT + b * 256 + c * 4 + r] = 1.f / (1.f + expf(-acc));
    }
}

// ---------------- main: R15 structure + packed-FMA pass 1 (gpack8) ----------------
// R16 lesson: global_load_lds staging raced on replay -> reverted to R15's
// register-batched phase staging (proven clean). This round's single change:
// pass-1 guide conv uses v_pk_fma_f32 pairs (rg even/odd share n[k]) via
// float2 elementwise fma. Per-component fmaf chains are BIT-IDENTICAL to
// R15/R13 (argmax-safe; R13 validated this accumulation order). gpack8
// layout cuts weight b128s 24->18/channel; LDS 54.3 -> 46.1 KB.
__global__ __launch_bounds__(256, 2)
void da_main(const float* __restrict__ x0,
             const float* __restrict__ ws,
             const float* __restrict__ g1b,
             const float* __restrict__ g2b,
             const float* __restrict__ convb,
             float* __restrict__ out)
{
    const int b  = blockIdx.z;
    const int h0 = blockIdx.y * TH;
    const int w0 = blockIdx.x * TW;
    const int tid = threadIdx.x;
    const int tx = tid & (TW - 1);
    const int ty = tid >> 5;
    const int lane = tid & 63;
    const int wave = tid >> 6;

    // swts: pass1 = gpack8 [c][k][8] (4608 fl); pass2 = skern[0,2304)+satt[2304,2560)
    __shared__ __align__(16) float swts[4608];            // 18,432 B
    // pool: sx float[2720] @0 | rbuf [wave][64pix][32ch] bf16 @10880 (16 KB)
    // after GEMM: pool dead -> sy transpose (4 x 1088 fl)
    __shared__ __align__(16) char pool[27264];
    float* sx = (float*)pool;
    char*  rbuf = pool + 10880;
    // total 46,080 B

    const float* xb  = x0 + (size_t)b * Cx * HWx;
    const float* kws = ws + WS_KERN + b * 2304;
    const float* aws = ws + WS_ATT  + b * 256;
    const unsigned int* wsu = (const unsigned int*)ws;

    // --- per-thread staging offsets, computed ONCE (named ints, no array) ---
    int o0, o1, o2, o3, o4, o5, o6, o7, o8, o9, o10;
    unsigned vmask = 0u;
#define MKOFF(i, oname)                                                        \
    do {                                                                       \
        const int e   = tid + (i) * 256;                                       \
        const int cc  = e / CPLANE;                                            \
        const int rem = e - cc * CPLANE;                                       \
        const int row = rem / HALO_W;                                          \
        const int col = rem - row * HALO_W;                                    \
        const int gh  = h0 - 1 + row;                                          \
        const int gw  = w0 - 1 + col;                                          \
        oname = cc * HWx + gh * Wx + gw;                                       \
        if (e < CHUNK_ELEMS && (unsigned)gh < Hx && (unsigned)gw < Wx)         \
            vmask |= (1u << (i));                                              \
    } while (0)
    MKOFF(0, o0);  MKOFF(1, o1);  MKOFF(2, o2);  MKOFF(3, o3);
    MKOFF(4, o4);  MKOFF(5, o5);  MKOFF(6, o6);  MKOFF(7, o7);
    MKOFF(8, o8);  MKOFF(9, o9);  MKOFF(10, o10);
#undef MKOFF

    // batched staging: issue all loads, then all LDS writes (R10-proven)
#define STAGE_CHUNK(ch)                                                        \
    do {                                                                       \
        const float* src = xb + (size_t)(ch) * CCH * HWx;                      \
        float v0 = 0.f, v1 = 0.f, v2 = 0.f, v3 = 0.f, v4 = 0.f, v5 = 0.f;     \
        float v6 = 0.f, v7 = 0.f, v8 = 0.f, v9 = 0.f, v10 = 0.f;              \
        if (vmask & 1u)      v0  = src[o0];                                    \
        if (vmask & 2u)      v1  = src[o1];                                    \
        if (vmask & 4u)      v2  = src[o2];                                    \
        if (vmask & 8u)      v3  = src[o3];                                    \
        if (vmask & 16u)     v4  = src[o4];                                    \
        if (vmask & 32u)     v5  = src[o5];                                    \
        if (vmask & 64u)     v6  = src[o6];                                    \
        if (vmask & 128u)    v7  = src[o7];                                    \
        if (vmask & 256u)    v8  = src[o8];                                    \
        if (vmask & 512u)    v9  = src[o9];                                    \
        if (vmask & 1024u)   v10 = src[o10];                                   \
        sx[tid]           = v0;   sx[tid + 256]  = v1;                         \
        sx[tid + 512]     = v2;   sx[tid + 768]  = v3;                         \
        sx[tid + 1024]    = v4;   sx[tid + 1280] = v5;                         \
        sx[tid + 1536]    = v6;   sx[tid + 1792] = v7;                         \
        sx[tid + 2048]    = v8;   sx[tid + 2304] = v9;                         \
        if (tid < CHUNK_ELEMS - 2560) sx[tid + 2560] = v10;                    \
    } while (0)

    // --- prologue: gpack8 (1152 float4) batched into LDS (R13-validated) ---
    {
        const float4* s4 = (const float4*)(ws + WS_GPACK);
        float4* d4 = (float4*)swts;
        const float4 g0 = s4[tid], g1 = s4[tid + 256];
        const float4 g2 = s4[tid + 512], g3 = s4[tid + 768];
        float4 g4 = (float4){0.f, 0.f, 0.f, 0.f};
        if (tid < 128) g4 = s4[tid + 1024];
        d4[tid] = g0; d4[tid + 256] = g1; d4[tid + 512] = g2; d4[tid + 768] = g3;
        if (tid < 128) d4[tid + 1024] = g4;
    }

    // ================= PASS 1: guide convs -> argmax (packed FMA) =================
    float ga[8];
    #pragma unroll
    for (int r = 0; r < 4; ++r) { ga[r] = g1b[r]; ga[4 + r] = g2b[r]; }

    #pragma unroll 1
    for (int ch = 0; ch < NCHUNK; ++ch) {
        __syncthreads();
        STAGE_CHUNK(ch);
        __syncthreads();

        float pg[8] = {0.f, 0.f, 0.f, 0.f, 0.f, 0.f, 0.f, 0.f};
        #pragma unroll
        for (int cc = 0; cc < CCH; ++cc) {
            const int c = ch * CCH + cc;
            float n[9];
            #pragma unroll
            for (int kh = 0; kh < 3; ++kh)
                #pragma unroll
                for (int kw = 0; kw < 3; ++kw)
                    n[kh * 3 + kw] = sx[cc * CPLANE + (ty + kh) * HALO_W + (tx + kw)];
            const float4* wp = (const float4*)(swts + c * 72);
            // 4 packed accumulators: pairs (rg0,rg1)(rg2,rg3)(rg4,rg5)(rg6,rg7).
            // Each component's fmaf chain is k-ascending from 0 — bit-identical
            // to the scalar version (R13-validated accumulation order).
            f32x2 a0 = {0.f, 0.f}, a1 = {0.f, 0.f}, a2 = {0.f, 0.f}, a3 = {0.f, 0.f};
            #pragma unroll
            for (int k = 0; k < 9; ++k) {
                const float4 q0 = wp[k * 2];       // rg0..3 at this k
                const float4 q1 = wp[k * 2 + 1];   // rg4..7 at this k
                const f32x2 nn = {n[k], n[k]};
                a0 = __builtin_elementwise_fma(nn, (f32x2){q0.x, q0.y}, a0);
                a1 = __builtin_elementwise_fma(nn, (f32x2){q0.z, q0.w}, a1);
                a2 = __builtin_elementwise_fma(nn, (f32x2){q1.x, q1.y}, a2);
                a3 = __builtin_elementwise_fma(nn, (f32x2){q1.z, q1.w}, a3);
            }
            // rg = r*2+g -> pg index r + g*4
            pg[0] += a0.x; pg[4] += a0.y;
            pg[1] += a1.x; pg[5] += a1.y;
            pg[2] += a2.x; pg[6] += a2.y;
            pg[3] += a3.x; pg[7] += a3.y;
        }
        #pragma unroll
        for (int i = 0; i < 8; ++i) ga[i] += pg[i];
    }

    int r1 = 0, r2 = 0;
    {
        float m = ga[0];
        #pragma unroll
        for (int r = 1; r < 4; ++r) if (ga[r] > m) { m = ga[r]; r1 = r; }   // first-max ties
        float m2 = ga[4];
        #pragma unroll
        for (int r = 1; r < 4; ++r) if (ga[4 + r] > m2) { m2 = ga[4 + r]; r2 = r; }
    }

    // --- pass transition: overlay skern+satt into swts (batched, R12) ---
    __syncthreads();
    {
        const float4* k4 = (const float4*)kws;
        const float4 k0 = k4[tid], k1 = k4[tid + 256];
        const float kt = kws[2048 + tid];
        const float at = aws[tid];
        float4* kd4 = (float4*)swts;                  // skern at 0
        kd4[tid] = k0; kd4[tid + 256] = k1;
        swts[2048 + tid] = kt;                        // skern tail
        swts[2304 + tid] = at;                        // satt
    }
    // visibility: pass-2 loop-top barrier

    // ================= PASS 2: depthwise -> bf16 rbuf, K-split GEMM (R15) =================
#define DW_CHUNK(ch)                                                           \
    do {                                                                       \
        unsigned int us[4] = {0u, 0u, 0u, 0u};                                 \
        _Pragma("unroll")                                                      \
        for (int cc = 0; cc < CCH; ++cc) {                                     \
            const int c = (ch) * CCH + cc;                                     \
            float n[9];                                                        \
            _Pragma("unroll")                                                  \
            for (int kh = 0; kh < 3; ++kh)                                     \
                _Pragma("unroll")                                              \
                for (int kw = 0; kw < 3; ++kw)                                 \
                    n[kh * 3 + kw] = sx[cc * CPLANE + (ty + kh) * HALO_W + (tx + kw)]; \
            float dw = 0.f;                                                    \
            _Pragma("unroll")                                                  \
            for (int k = 0; k < 9; ++k)                                        \
                dw = fmaf(n[k], swts[c * 36 + k * 4 + r1], dw);                \
            const float routed = dw > 0.f ? dw : 0.1f * dw;                    \
            us[cc >> 1] |= rne_bf16(routed) << ((cc & 1) * 16);                \
        }                                                                      \
        const int byteoff = wave * 4096 + lane * 64 +                          \
                            ((((ch) & 3) ^ RSWZ(lane)) << 4);                  \
        *(u32x4*)(rbuf + byteoff) = (u32x4){us[0], us[1], us[2], us[3]};       \
    } while (0)

    f32x4 acc[4][4];

#define GEMM_HALF(ks)                                                          \
    do {                                                                       \
        const bf16x8* bglob = (const bf16x8*)(wsu + WS_CWB);                   \
        bf16x8 av[4];                                                          \
        _Pragma("unroll")                                                      \
        for (int mt = 0; mt < 4; ++mt) {                                       \
            const int pix = mt * 16 + (lane & 15);                             \
            const int sk = lane >> 4;                                          \
            av[mt] = *(const bf16x8*)(rbuf + wave * 4096 + pix * 64 +          \
                                      ((sk ^ RSWZ(pix)) << 4));                \
        }                                                                      \
        bf16x8 bv[4];                                                          \
        _Pragma("unroll")                                                      \
        for (int nt = 0; nt < 4; ++nt)                                         \
            bv[nt] = bglob[(nt * 2 + (ks)) * 64 + lane];                       \
        _Pragma("unroll")                                                      \
        for (int mt = 0; mt < 4; ++mt)                                         \
            _Pragma("unroll")                                                  \
            for (int nt = 0; nt < 4; ++nt)                                     \
                acc[mt][nt] = __builtin_amdgcn_mfma_f32_16x16x32_bf16(         \
                    av[mt], bv[nt], acc[mt][nt], 0, 0, 0);                     \
    } while (0)

    #pragma unroll 1
    for (int ch = 0; ch < 4; ++ch) {
        __syncthreads();
        STAGE_CHUNK(ch);
        __syncthreads();
        DW_CHUNK(ch);
    }
    #pragma unroll
    for (int mt = 0; mt < 4; ++mt)
        #pragma unroll
        for (int nt = 0; nt < 4; ++nt)
            acc[mt][nt] = (f32x4){0.f, 0.f, 0.f, 0.f};
    GEMM_HALF(0);          // same-wave rbuf write->read: in-order DS

    #pragma unroll 1
    for (int ch = 4; ch < 8; ++ch) {
        __syncthreads();
        STAGE_CHUNK(ch);
        __syncthreads();
        DW_CHUNK(ch);
    }
    GEMM_HALF(1);

    __syncthreads();       // all sx/rbuf reads done: pool becomes sy

    // --- epilogue per nt-group: padded transpose + store (R13-validated) ---
    const int hh = h0 + ty;
    const int ww = w0 + tx;
    float* op = out + (size_t)b * Cx * HWx + hh * Wx + ww;
    const float* xp = xb + hh * Wx + ww;
    float* syw = (float*)pool + wave * 1088;
    #pragma unroll
    for (int nt = 0; nt < 4; ++nt) {
        #pragma unroll
        for (int mt = 0; mt < 4; ++mt)
            #pragma unroll
            for (int q = 0; q < 4; ++q)
                syw[(mt * 16 + (lane >> 4) * 4 + q) * 17 + (lane & 15)] = acc[mt][nt][q];
        #pragma unroll
        for (int t = 0; t < 16; ++t) {
            const int o = nt * 16 + t;
            const float v = syw[lane * 17 + t] + convb[o]
                          + xp[(size_t)o * HWx] * swts[2304 + o * 4 + r2];
            op[(size_t)o * HWx] = v;
        }
    }
}

extern "C" void kernel_launch(void* const* d_in, const int* in_sizes, int n_in,
                              void* d_out, int out_size, void* d_ws, size_t ws_size,
                              hipStream_t stream) {
    const float* x0     = (const float*)d_in[0];
    const float* x_deg  = (const float*)d_in[1];
    const float* kw1    = (const float*)d_in[2];
    const float* kw2    = (const float*)d_in[3];
    const float* convw  = (const float*)d_in[4];
    const float* convb  = (const float*)d_in[5];
    const float* ca_w1  = (const float*)d_in[6];
    const float* ca_w2  = (const float*)d_in[7];
    const float* g1w    = (const float*)d_in[8];
    const float* g1b    = (const float*)d_in[9];
    const float* g2w    = (const float*)d_in[10];
    const float* g2b    = (const float*)d_in[11];
    float* outp = (float*)d_out;
    float* wsf  = (float*)d_ws;

    da_prep<<<Bx + 1, 256, 0, stream>>>(x_deg, kw1, kw2, convw, ca_w1, ca_w2,
                                        g1w, g2w, wsf);

    dim3 grid(Wx / TW, Hx / TH, Bx);   // 4 x 16 x 16 = 1024 blocks
    da_main<<<grid, 256, 0, stream>>>(x0, wsf, g1b, g2b, convb, outp);
}